// Round 7
// baseline (138.149 us; speedup 1.0000x reference)
//
#include <hip/hip_runtime.h>
#include <math.h>

#define N_BINS 229
#define MODEL  128
#define OUTD   88
#define WSZ    30
#define WLEN   61
#define BB     4
#define TT     2048
#define CTANH  2.8853900817779268f   // 2*log2(e)

__device__ __forceinline__ float sigmoidf_(float x) {
    return __builtin_amdgcn_rcpf(1.0f + __expf(-x));
}

// ---------------- Pass 1: H = spec@W_h + b_attn ; E = spec@W_e ----------------
// 8 rows/block in LDS; thread = output column; W loads double-buffered (8 deep).
#define ROWS_HE 8
__global__ __launch_bounds__(256, 8) void k_he(
        const float* __restrict__ spec,
        const float* __restrict__ W_h,
        const float* __restrict__ W_e,
        const float* __restrict__ b_attn,
        float* __restrict__ H,
        float* __restrict__ E) {
    const int tid = threadIdx.x;
    __shared__ float s[ROWS_HE * N_BINS];              // 7328 B
    const float4* __restrict__ src4 =
        (const float4*)(spec + (size_t)blockIdx.x * (ROWS_HE * N_BINS));
    float4* s4 = (float4*)s;
#pragma unroll
    for (int i = 0; i < 2; ++i) {
        int idx = i * 256 + tid;
        if (idx < (ROWS_HE * N_BINS) / 4) s4[idx] = src4[idx];
    }
    __syncthreads();

    const int  m   = tid & 127;
    const bool isH = tid < 128;
    const float* __restrict__ Wp = (isH ? W_h : W_e) + m;
    const float bias = isH ? b_attn[m] : 0.0f;

    float acc[ROWS_HE];
#pragma unroll
    for (int r = 0; r < ROWS_HE; ++r) acc[r] = 0.0f;

    float cur[8];
#pragma unroll
    for (int j = 0; j < 8; ++j) cur[j] = Wp[j * MODEL];

    for (int batch = 0; batch < 28; ++batch) {         // 28*8 = 224
        const int fb = batch * 8;
        float nxt[8];
        if (batch < 27) {
#pragma unroll
            for (int j = 0; j < 8; ++j) nxt[j] = Wp[(fb + 8 + j) * MODEL];
        }
#pragma unroll
        for (int j = 0; j < 8; ++j) {
            const float wv = cur[j];
#pragma unroll
            for (int r = 0; r < ROWS_HE; ++r)
                acc[r] = fmaf(s[r * N_BINS + fb + j], wv, acc[r]);
        }
        if (batch < 27) {
#pragma unroll
            for (int j = 0; j < 8; ++j) cur[j] = nxt[j];
        }
    }
    for (int f = 224; f < N_BINS; ++f) {               // 5-wide tail
        const float wv = Wp[f * MODEL];
#pragma unroll
        for (int r = 0; r < ROWS_HE; ++r)
            acc[r] = fmaf(s[r * N_BINS + f], wv, acc[r]);
    }

    float* __restrict__ dst =
        (isH ? H : E) + (size_t)blockIdx.x * ROWS_HE * MODEL + m;
#pragma unroll
    for (int r = 0; r < ROWS_HE; ++r) dst[r * MODEL] = acc[r] + bias;
}

// ---------------- score for a ROW PAIR (t, t+1), 2-deep E prefetch ----------------
template <bool SAFE>
__device__ __forceinline__ void score_pair(
        const float4* __restrict__ Eb4,     // batch base (rows of 32 float4)
        const float4* __restrict__ HsT,     // H row t   (32 float4, LDS)
        const float4* __restrict__ HsU,     // H row t+1 (32 float4, LDS)
        const float4* __restrict__ Vs4,     // v_w (32 float4, LDS)
        int t, int g, int w0,
        float* __restrict__ scT, float* __restrict__ scU) {
    const float4* er[4];
    bool ok[4];
#pragma unroll
    for (int it = 0; it < 4; ++it) {
        const int w = w0 + it * 16;
        const int s = t + w - WSZ;
        if (SAFE) {
            ok[it] = (s >= 0) && (s < TT);
            er[it] = Eb4 + (size_t)min(max(s, 0), TT - 1) * 32 + g;
        } else {
            er[it] = Eb4 + (size_t)s * 32 + g;   // t in [30,2014]: s in [0,2047]
        }
    }

    float ppT[4] = {0.f, 0.f, 0.f, 0.f};
    float ppU[4] = {0.f, 0.f, 0.f, 0.f};
    float vs = 0.f;

    float4 evn[4];                                     // prefetch q=0
#pragma unroll
    for (int it = 0; it < 4; ++it) {
        float4 v = er[it][0];
        if (SAFE && !ok[it]) v = make_float4(0.f, 0.f, 0.f, 0.f);
        evn[it] = v;
    }

#pragma unroll
    for (int q = 0; q < 8; ++q) {
        float4 evc[4];
#pragma unroll
        for (int it = 0; it < 4; ++it) evc[it] = evn[it];
        if (q < 7) {
#pragma unroll
            for (int it = 0; it < 4; ++it) {           // prefetch q+1
                float4 v = er[it][(q + 1) << 2];
                if (SAFE && !ok[it]) v = make_float4(0.f, 0.f, 0.f, 0.f);
                evn[it] = v;
            }
        }
        const int    cq = (q << 2) + g;
        const float4 hT = HsT[cq];
        const float4 hU = HsU[cq];
        const float4 vq = Vs4[cq];
        vs += (vq.x + vq.y) + (vq.z + vq.w);
        const float nx = -2.f * vq.x, ny = -2.f * vq.y,
                    nz = -2.f * vq.z, nw = -2.f * vq.w;
        const float aTx = hT.x * CTANH, aTy = hT.y * CTANH,
                    aTz = hT.z * CTANH, aTw = hT.w * CTANH;
        const float aUx = hU.x * CTANH, aUy = hU.y * CTANH,
                    aUz = hU.z * CTANH, aUw = hU.w * CTANH;
#pragma unroll
        for (int it = 0; it < 4; ++it) {
            const float4 ev = evc[it];
            const float ex = ev.x * CTANH, ey = ev.y * CTANH,
                        ez = ev.z * CTANH, ew = ev.w * CTANH;
            float u;
            u = __builtin_amdgcn_rcpf(__builtin_amdgcn_exp2f(ex + aTx) + 1.f);
            ppT[it] = fmaf(nx, u, ppT[it]);
            u = __builtin_amdgcn_rcpf(__builtin_amdgcn_exp2f(ex + aUx) + 1.f);
            ppU[it] = fmaf(nx, u, ppU[it]);
            u = __builtin_amdgcn_rcpf(__builtin_amdgcn_exp2f(ey + aTy) + 1.f);
            ppT[it] = fmaf(ny, u, ppT[it]);
            u = __builtin_amdgcn_rcpf(__builtin_amdgcn_exp2f(ey + aUy) + 1.f);
            ppU[it] = fmaf(ny, u, ppU[it]);
            u = __builtin_amdgcn_rcpf(__builtin_amdgcn_exp2f(ez + aTz) + 1.f);
            ppT[it] = fmaf(nz, u, ppT[it]);
            u = __builtin_amdgcn_rcpf(__builtin_amdgcn_exp2f(ez + aUz) + 1.f);
            ppU[it] = fmaf(nz, u, ppU[it]);
            u = __builtin_amdgcn_rcpf(__builtin_amdgcn_exp2f(ew + aTw) + 1.f);
            ppT[it] = fmaf(nw, u, ppT[it]);
            u = __builtin_amdgcn_rcpf(__builtin_amdgcn_exp2f(ew + aUw) + 1.f);
            ppU[it] = fmaf(nw, u, ppU[it]);
        }
    }

    vs += __shfl_xor(vs, 1, 64);
    vs += __shfl_xor(vs, 2, 64);
#pragma unroll
    for (int it = 0; it < 4; ++it) {
        float pT = ppT[it];
        pT += __shfl_xor(pT, 1, 64);
        pT += __shfl_xor(pT, 2, 64);
        float pU = ppU[it];
        pU += __shfl_xor(pU, 1, 64);
        pU += __shfl_xor(pU, 2, 64);
        const int w = w0 + it * 16;
        if (g == 0) {
            if (w < WLEN)            scT[w]     = pT + vs;
            if (w >= 1 && w <= WLEN) scU[w - 1] = pU + vs;
        }
    }
}

// ---------------- Pass 2a: scores + softmax -> aEff (into H region) ----------------
// aEff for pair p lives at H + p*256: [0..63]=row-T aEff, [64..127]=row-U shifted.
// Safe: each k_score block reads only its own 8 H rows (staged before writes).
__global__ __launch_bounds__(256, 5) void k_score(
        const float* __restrict__ H,
        const float* __restrict__ E,
        const float* __restrict__ v_w,
        float* __restrict__ aeff,           // == H base
        float* __restrict__ a_out) {
    const int tid  = threadIdx.x;
    const int wv   = tid >> 6;
    const int lane = tid & 63;
    const int r0   = blockIdx.x * 8;
    const int p    = blockIdx.x * 4 + wv;   // pair index
    const int rT   = r0 + wv * 2;
    const int b    = rT >> 11;              // T = 2048
    const int t    = rT & (TT - 1);

    __shared__ float4 Hs4[8 * 32];          // 4 KB
    __shared__ float4 Vs4[32];              // 512 B
    __shared__ float  scA[4][2][64];        // 2 KB

    Hs4[tid] = ((const float4*)H)[(size_t)r0 * 32 + tid];
    if (tid < 32) Vs4[tid] = ((const float4*)v_w)[tid];
    __syncthreads();

    const int g  = lane & 3;
    const int w0 = lane >> 2;
    const float4* __restrict__ Eb4 = (const float4*)E + (size_t)b * TT * 32;

    if (t >= WSZ && t <= TT - 1 - 33)
        score_pair<false>(Eb4, &Hs4[(wv * 2) * 32], &Hs4[(wv * 2 + 1) * 32],
                          Vs4, t, g, w0, scA[wv][0], scA[wv][1]);
    else
        score_pair<true >(Eb4, &Hs4[(wv * 2) * 32], &Hs4[(wv * 2 + 1) * 32],
                          Vs4, t, g, w0, scA[wv][0], scA[wv][1]);

    float* __restrict__ ap = aeff + (size_t)p * 256;
#pragma unroll
    for (int rr = 0; rr < 2; ++rr) {
        float x = (lane < WLEN) ? scA[wv][rr][lane] : -INFINITY;
        float mx = x;
#pragma unroll
        for (int d = 32; d >= 1; d >>= 1) mx = fmaxf(mx, __shfl_xor(mx, d, 64));
        float e = (lane < WLEN) ? __expf(x - mx) : 0.0f;
        float sm = e;
#pragma unroll
        for (int d = 32; d >= 1; d >>= 1) sm += __shfl_xor(sm, d, 64);
        const float a = e * __builtin_amdgcn_rcpf(sm);
        if (lane < WLEN) a_out[(size_t)(rT + rr) * WLEN + lane] = a;
        const int   sl   = (t + rr) + lane - WSZ;
        const float aval = (lane < WLEN && sl >= 0 && sl < TT) ? a : 0.0f;
        if (rr == 0) {
            ap[lane] = aval;                               // slots 61..63 = 0
        } else {
            const float sh = __shfl_up(aval, 1, 64);       // aU[w] = a_{t+1}[w-1]
            ap[64 + lane] = (lane >= 1 && lane <= WLEN) ? sh : 0.0f;
        }
    }
}

// ---------------- Pass 2b: pooling + gemv + sigmoid ----------------
__global__ __launch_bounds__(256, 8) void k_pool(
        const float* __restrict__ spec,
        const float* __restrict__ aeff,     // == H base
        const float* __restrict__ W1,
        const float* __restrict__ b1,
        float* __restrict__ pred) {
    const int tid  = threadIdx.x;
    const int wv   = tid >> 6;
    const int lane = tid & 63;
    const int r0   = blockIdx.x * 8;
    const int p    = blockIdx.x * 4 + wv;
    const int rT   = r0 + wv * 2;
    const int b    = rT >> 11;
    const int t    = rT & (TT - 1);

    __shared__ float scA[4][2][64];         // 2 KB
    __shared__ float wsum[4][2][232];       // 7.4 KB

    const float* __restrict__ ap = aeff + (size_t)p * 256;
    scA[wv][0][lane] = ap[lane];
    scA[wv][1][lane] = ap[64 + lane];       // same-wave write->read, no barrier

    const float* __restrict__ sb = spec + (size_t)b * TT * N_BINS;
    float t0a = 0.f, t1a = 0.f, t2a = 0.f, t3a = 0.f;
    float u0a = 0.f, u1a = 0.f, u2a = 0.f, u3a = 0.f;
    const int f3 = (lane < 37) ? lane + 192 : 228;
#pragma unroll 4
    for (int w2 = 0; w2 < 62; ++w2) {
        const float at = scA[wv][0][w2];    // LDS broadcast
        const float au = scA[wv][1][w2];
        const int   s2 = min(max(t + w2 - WSZ, 0), TT - 1);
        const float* __restrict__ row = sb + (size_t)s2 * N_BINS;
        const float c0 = row[lane      ];
        const float c1 = row[lane +  64];
        const float c2 = row[lane + 128];
        const float c3 = row[f3        ];
        t0a = fmaf(at, c0, t0a);  u0a = fmaf(au, c0, u0a);
        t1a = fmaf(at, c1, t1a);  u1a = fmaf(au, c1, u1a);
        t2a = fmaf(at, c2, t2a);  u2a = fmaf(au, c2, u2a);
        t3a = fmaf(at, c3, t3a);  u3a = fmaf(au, c3, u3a);
    }
    wsum[wv][0][lane      ] = t0a;   wsum[wv][1][lane      ] = u0a;
    wsum[wv][0][lane +  64] = t1a;   wsum[wv][1][lane +  64] = u1a;
    wsum[wv][0][lane + 128] = t2a;   wsum[wv][1][lane + 128] = u2a;
    if (lane < 37) { wsum[wv][0][lane + 192] = t3a; wsum[wv][1][lane + 192] = u3a; }

    __syncthreads();

    // ---- gemv: 176 threads, 4 rows each; 8-deep W1 register prefetch ----
    if (tid < 176) {
        const int h = (tid >= 88) ? 1 : 0;
        const int o = tid - h * 88;
        const float* __restrict__ ws = &wsum[0][0][0] + h * 4 * 232;
        float acc0 = b1[o], acc1 = acc0, acc2 = acc0, acc3 = acc0;
        const float* __restrict__ W1o = W1 + o;

        float cur[8];
#pragma unroll
        for (int j = 0; j < 8; ++j) cur[j] = W1o[j * OUTD];

        for (int batch = 0; batch < 28; ++batch) {     // 28*8 = 224
            const int fb = batch * 8;
            float nxt[8];
            if (batch < 27) {
#pragma unroll
                for (int j = 0; j < 8; ++j) nxt[j] = W1o[(fb + 8 + j) * OUTD];
            }
#pragma unroll
            for (int j = 0; j < 8; ++j) {
                const float w1v = cur[j];
                const int   f   = fb + j;
                acc0 = fmaf(ws[f      ], w1v, acc0);
                acc1 = fmaf(ws[f + 232], w1v, acc1);
                acc2 = fmaf(ws[f + 464], w1v, acc2);
                acc3 = fmaf(ws[f + 696], w1v, acc3);
            }
            if (batch < 27) {
#pragma unroll
                for (int j = 0; j < 8; ++j) cur[j] = nxt[j];
            }
        }
        for (int f = 224; f < N_BINS; ++f) {
            const float w1v = W1o[f * OUTD];
            acc0 = fmaf(ws[f      ], w1v, acc0);
            acc1 = fmaf(ws[f + 232], w1v, acc1);
            acc2 = fmaf(ws[f + 464], w1v, acc2);
            acc3 = fmaf(ws[f + 696], w1v, acc3);
        }
        const size_t rb = (size_t)r0 + h * 4;
        pred[(rb + 0) * OUTD + o] = sigmoidf_(acc0);
        pred[(rb + 1) * OUTD + o] = sigmoidf_(acc1);
        pred[(rb + 2) * OUTD + o] = sigmoidf_(acc2);
        pred[(rb + 3) * OUTD + o] = sigmoidf_(acc3);
    }
}

extern "C" void kernel_launch(void* const* d_in, const int* in_sizes, int n_in,
                              void* d_out, int out_size, void* d_ws, size_t ws_size,
                              hipStream_t stream) {
    const float* spec   = (const float*)d_in[0];
    const float* W_h    = (const float*)d_in[1];
    const float* W_e    = (const float*)d_in[2];
    const float* b_attn = (const float*)d_in[3];
    const float* v_w    = (const float*)d_in[4];
    const float* W1     = (const float*)d_in[5];
    const float* b1     = (const float*)d_in[6];

    const int n_rows = BB * TT;                    // 8192
    float* H = (float*)d_ws;                       // 4 MB (reused as aEff)
    float* E = H + (size_t)n_rows * MODEL;         // 4 MB

    float* pred  = (float*)d_out;                  // 8192*88
    float* a_out = pred + (size_t)n_rows * OUTD;   // 8192*61

    k_he   <<<n_rows / ROWS_HE, 256, 0, stream>>>(spec, W_h, W_e, b_attn, H, E);
    k_score<<<n_rows / 8,       256, 0, stream>>>(H, E, v_w, H, a_out);
    k_pool <<<n_rows / 8,       256, 0, stream>>>(spec, H, W1, b1, pred);
}

// Round 8
// 131.806 us; speedup vs baseline: 1.0481x; 1.0481x over previous
//
#include <hip/hip_runtime.h>
#include <math.h>

#define N_BINS 229
#define MODEL  128
#define OUTD   88
#define WSZ    30
#define WLEN   61
#define BB     4
#define TT     2048
#define CTANH  2.8853900817779268f   // 2*log2(e)

__device__ __forceinline__ float sigmoidf_(float x) {
    return __builtin_amdgcn_rcpf(1.0f + __expf(-x));
}

// Bijective XCD swizzle (nwg % 8 == 0): XCD i owns logical blocks
// [i*nwg/8, (i+1)*nwg/8) -> consecutive-t blocks share one XCD's L2.
__device__ __forceinline__ int xcd_swz(int x, int nwg) {
    return (x & 7) * (nwg >> 3) + (x >> 3);
}

// ---------------- Pass 1: H = spec@W_h + b_attn ; E = spec@W_e ----------------
// 8 rows/block in LDS; thread = output column; W loads double-buffered (8 deep).
#define ROWS_HE 8
__global__ __launch_bounds__(256, 8) void k_he(
        const float* __restrict__ spec,
        const float* __restrict__ W_h,
        const float* __restrict__ W_e,
        const float* __restrict__ b_attn,
        float* __restrict__ H,
        float* __restrict__ E) {
    const int nb  = xcd_swz(blockIdx.x, gridDim.x);
    const int tid = threadIdx.x;
    __shared__ float s[ROWS_HE * N_BINS];              // 7328 B
    const float4* __restrict__ src4 =
        (const float4*)(spec + (size_t)nb * (ROWS_HE * N_BINS));
    float4* s4 = (float4*)s;
#pragma unroll
    for (int i = 0; i < 2; ++i) {
        int idx = i * 256 + tid;
        if (idx < (ROWS_HE * N_BINS) / 4) s4[idx] = src4[idx];
    }
    __syncthreads();

    const int  m   = tid & 127;
    const bool isH = tid < 128;
    const float* __restrict__ Wp = (isH ? W_h : W_e) + m;
    const float bias = isH ? b_attn[m] : 0.0f;

    float acc[ROWS_HE];
#pragma unroll
    for (int r = 0; r < ROWS_HE; ++r) acc[r] = 0.0f;

    float cur[8];
#pragma unroll
    for (int j = 0; j < 8; ++j) cur[j] = Wp[j * MODEL];

    for (int batch = 0; batch < 28; ++batch) {         // 28*8 = 224
        const int fb = batch * 8;
        float nxt[8];
        if (batch < 27) {
#pragma unroll
            for (int j = 0; j < 8; ++j) nxt[j] = Wp[(fb + 8 + j) * MODEL];
        }
#pragma unroll
        for (int j = 0; j < 8; ++j) {
            const float wv = cur[j];
#pragma unroll
            for (int r = 0; r < ROWS_HE; ++r)
                acc[r] = fmaf(s[r * N_BINS + fb + j], wv, acc[r]);
        }
        if (batch < 27) {
#pragma unroll
            for (int j = 0; j < 8; ++j) cur[j] = nxt[j];
        }
    }
    for (int f = 224; f < N_BINS; ++f) {               // 5-wide tail
        const float wv = Wp[f * MODEL];
#pragma unroll
        for (int r = 0; r < ROWS_HE; ++r)
            acc[r] = fmaf(s[r * N_BINS + f], wv, acc[r]);
    }

    float* __restrict__ dst =
        (isH ? H : E) + (size_t)nb * ROWS_HE * MODEL + m;
#pragma unroll
    for (int r = 0; r < ROWS_HE; ++r) dst[r * MODEL] = acc[r] + bias;
}

// ---------------- score for a ROW PAIR (t, t+1), 2-deep E prefetch ----------------
template <bool SAFE>
__device__ __forceinline__ void score_pair(
        const float4* __restrict__ Eb4,     // batch base (rows of 32 float4)
        const float4* __restrict__ HsT,     // H row t   (32 float4, LDS)
        const float4* __restrict__ HsU,     // H row t+1 (32 float4, LDS)
        const float4* __restrict__ Vs4,     // v_w (32 float4, LDS)
        int t, int g, int w0,
        float* __restrict__ scT, float* __restrict__ scU) {
    const float4* er[4];
    bool ok[4];
#pragma unroll
    for (int it = 0; it < 4; ++it) {
        const int w = w0 + it * 16;
        const int s = t + w - WSZ;
        if (SAFE) {
            ok[it] = (s >= 0) && (s < TT);
            er[it] = Eb4 + (size_t)min(max(s, 0), TT - 1) * 32 + g;
        } else {
            er[it] = Eb4 + (size_t)s * 32 + g;   // t in [30,2014]: s in [0,2047]
        }
    }

    float ppT[4] = {0.f, 0.f, 0.f, 0.f};
    float ppU[4] = {0.f, 0.f, 0.f, 0.f};
    float vs = 0.f;

    float4 evn[4];                                     // prefetch q=0
#pragma unroll
    for (int it = 0; it < 4; ++it) {
        float4 v = er[it][0];
        if (SAFE && !ok[it]) v = make_float4(0.f, 0.f, 0.f, 0.f);
        evn[it] = v;
    }

#pragma unroll
    for (int q = 0; q < 8; ++q) {
        float4 evc[4];
#pragma unroll
        for (int it = 0; it < 4; ++it) evc[it] = evn[it];
        if (q < 7) {
#pragma unroll
            for (int it = 0; it < 4; ++it) {           // prefetch q+1
                float4 v = er[it][(q + 1) << 2];
                if (SAFE && !ok[it]) v = make_float4(0.f, 0.f, 0.f, 0.f);
                evn[it] = v;
            }
        }
        const int    cq = (q << 2) + g;
        const float4 hT = HsT[cq];
        const float4 hU = HsU[cq];
        const float4 vq = Vs4[cq];
        vs += (vq.x + vq.y) + (vq.z + vq.w);
        const float nx = -2.f * vq.x, ny = -2.f * vq.y,
                    nz = -2.f * vq.z, nw = -2.f * vq.w;
        const float aTx = hT.x * CTANH, aTy = hT.y * CTANH,
                    aTz = hT.z * CTANH, aTw = hT.w * CTANH;
        const float aUx = hU.x * CTANH, aUy = hU.y * CTANH,
                    aUz = hU.z * CTANH, aUw = hU.w * CTANH;
#pragma unroll
        for (int it = 0; it < 4; ++it) {
            const float4 ev = evc[it];
            const float ex = ev.x * CTANH, ey = ev.y * CTANH,
                        ez = ev.z * CTANH, ew = ev.w * CTANH;
            float u;
            u = __builtin_amdgcn_rcpf(__builtin_amdgcn_exp2f(ex + aTx) + 1.f);
            ppT[it] = fmaf(nx, u, ppT[it]);
            u = __builtin_amdgcn_rcpf(__builtin_amdgcn_exp2f(ex + aUx) + 1.f);
            ppU[it] = fmaf(nx, u, ppU[it]);
            u = __builtin_amdgcn_rcpf(__builtin_amdgcn_exp2f(ey + aTy) + 1.f);
            ppT[it] = fmaf(ny, u, ppT[it]);
            u = __builtin_amdgcn_rcpf(__builtin_amdgcn_exp2f(ey + aUy) + 1.f);
            ppU[it] = fmaf(ny, u, ppU[it]);
            u = __builtin_amdgcn_rcpf(__builtin_amdgcn_exp2f(ez + aTz) + 1.f);
            ppT[it] = fmaf(nz, u, ppT[it]);
            u = __builtin_amdgcn_rcpf(__builtin_amdgcn_exp2f(ez + aUz) + 1.f);
            ppU[it] = fmaf(nz, u, ppU[it]);
            u = __builtin_amdgcn_rcpf(__builtin_amdgcn_exp2f(ew + aTw) + 1.f);
            ppT[it] = fmaf(nw, u, ppT[it]);
            u = __builtin_amdgcn_rcpf(__builtin_amdgcn_exp2f(ew + aUw) + 1.f);
            ppU[it] = fmaf(nw, u, ppU[it]);
        }
    }

    vs += __shfl_xor(vs, 1, 64);
    vs += __shfl_xor(vs, 2, 64);
#pragma unroll
    for (int it = 0; it < 4; ++it) {
        float pT = ppT[it];
        pT += __shfl_xor(pT, 1, 64);
        pT += __shfl_xor(pT, 2, 64);
        float pU = ppU[it];
        pU += __shfl_xor(pU, 1, 64);
        pU += __shfl_xor(pU, 2, 64);
        const int w = w0 + it * 16;
        if (g == 0) {
            if (w < WLEN)            scT[w]     = pT + vs;
            if (w >= 1 && w <= WLEN) scU[w - 1] = pU + vs;
        }
    }
}

// ---------------- Pass 2a: scores + softmax -> aEff ----------------
// aEff for pair p at aeff + p*256: [0..63]=row-T aEff, [64..127]=row-U shifted.
__global__ __launch_bounds__(256, 5) void k_score(
        const float* __restrict__ H,
        const float* __restrict__ E,
        const float* __restrict__ v_w,
        float* __restrict__ aeff,
        float* __restrict__ a_out) {
    const int nb   = xcd_swz(blockIdx.x, gridDim.x);
    const int tid  = threadIdx.x;
    const int wv   = tid >> 6;
    const int lane = tid & 63;
    const int r0   = nb * 8;
    const int p    = nb * 4 + wv;           // pair index
    const int rT   = r0 + wv * 2;
    const int b    = rT >> 11;              // T = 2048
    const int t    = rT & (TT - 1);

    __shared__ float4 Hs4[8 * 32];          // 4 KB
    __shared__ float4 Vs4[32];              // 512 B
    __shared__ float  scA[4][2][64];        // 2 KB

    Hs4[tid] = ((const float4*)H)[(size_t)r0 * 32 + tid];
    if (tid < 32) Vs4[tid] = ((const float4*)v_w)[tid];
    __syncthreads();

    const int g  = lane & 3;
    const int w0 = lane >> 2;
    const float4* __restrict__ Eb4 = (const float4*)E + (size_t)b * TT * 32;

    if (t >= WSZ && t <= TT - 1 - 33)
        score_pair<false>(Eb4, &Hs4[(wv * 2) * 32], &Hs4[(wv * 2 + 1) * 32],
                          Vs4, t, g, w0, scA[wv][0], scA[wv][1]);
    else
        score_pair<true >(Eb4, &Hs4[(wv * 2) * 32], &Hs4[(wv * 2 + 1) * 32],
                          Vs4, t, g, w0, scA[wv][0], scA[wv][1]);

    float* __restrict__ ap = aeff + (size_t)p * 256;
#pragma unroll
    for (int rr = 0; rr < 2; ++rr) {
        float x = (lane < WLEN) ? scA[wv][rr][lane] : -INFINITY;
        float mx = x;
#pragma unroll
        for (int d = 32; d >= 1; d >>= 1) mx = fmaxf(mx, __shfl_xor(mx, d, 64));
        float e = (lane < WLEN) ? __expf(x - mx) : 0.0f;
        float sm = e;
#pragma unroll
        for (int d = 32; d >= 1; d >>= 1) sm += __shfl_xor(sm, d, 64);
        const float a = e * __builtin_amdgcn_rcpf(sm);
        if (lane < WLEN) a_out[(size_t)(rT + rr) * WLEN + lane] = a;
        const int   sl   = (t + rr) + lane - WSZ;
        const float aval = (lane < WLEN && sl >= 0 && sl < TT) ? a : 0.0f;
        if (rr == 0) {
            ap[lane] = aval;                               // slots 61..63 = 0
        } else {
            const float sh = __shfl_up(aval, 1, 64);       // aU[w] = a_{t+1}[w-1]
            ap[64 + lane] = (lane >= 1 && lane <= WLEN) ? sh : 0.0f;
        }
    }
}

// ---------------- Pass 2b: pooling + gemv + sigmoid ----------------
__global__ __launch_bounds__(256, 8) void k_pool(
        const float* __restrict__ spec,
        const float* __restrict__ aeff,
        const float* __restrict__ W1,
        const float* __restrict__ b1,
        float* __restrict__ pred) {
    const int nb   = xcd_swz(blockIdx.x, gridDim.x);
    const int tid  = threadIdx.x;
    const int wv   = tid >> 6;
    const int lane = tid & 63;
    const int r0   = nb * 8;
    const int p    = nb * 4 + wv;
    const int rT   = r0 + wv * 2;
    const int b    = rT >> 11;
    const int t    = rT & (TT - 1);

    __shared__ float scA[4][2][64];         // 2 KB
    __shared__ float wsum[4][2][232];       // 7.4 KB

    const float* __restrict__ ap = aeff + (size_t)p * 256;
    scA[wv][0][lane] = ap[lane];
    scA[wv][1][lane] = ap[64 + lane];       // same-wave write->read, no barrier

    const float* __restrict__ sb = spec + (size_t)b * TT * N_BINS;
    float t0a = 0.f, t1a = 0.f, t2a = 0.f, t3a = 0.f;
    float u0a = 0.f, u1a = 0.f, u2a = 0.f, u3a = 0.f;
    const int f3 = (lane < 37) ? lane + 192 : 228;
#pragma unroll 4
    for (int w2 = 0; w2 < 62; ++w2) {
        const float at = scA[wv][0][w2];    // LDS broadcast
        const float au = scA[wv][1][w2];
        const int   s2 = min(max(t + w2 - WSZ, 0), TT - 1);
        const float* __restrict__ row = sb + (size_t)s2 * N_BINS;
        const float c0 = row[lane      ];
        const float c1 = row[lane +  64];
        const float c2 = row[lane + 128];
        const float c3 = row[f3        ];
        t0a = fmaf(at, c0, t0a);  u0a = fmaf(au, c0, u0a);
        t1a = fmaf(at, c1, t1a);  u1a = fmaf(au, c1, u1a);
        t2a = fmaf(at, c2, t2a);  u2a = fmaf(au, c2, u2a);
        t3a = fmaf(at, c3, t3a);  u3a = fmaf(au, c3, u3a);
    }
    wsum[wv][0][lane      ] = t0a;   wsum[wv][1][lane      ] = u0a;
    wsum[wv][0][lane +  64] = t1a;   wsum[wv][1][lane +  64] = u1a;
    wsum[wv][0][lane + 128] = t2a;   wsum[wv][1][lane + 128] = u2a;
    if (lane < 37) { wsum[wv][0][lane + 192] = t3a; wsum[wv][1][lane + 192] = u3a; }

    __syncthreads();

    // ---- gemv: 176 threads, 4 rows each; 8-deep W1 register prefetch ----
    if (tid < 176) {
        const int h = (tid >= 88) ? 1 : 0;
        const int o = tid - h * 88;
        const float* __restrict__ ws = &wsum[0][0][0] + h * 4 * 232;
        float acc0 = b1[o], acc1 = acc0, acc2 = acc0, acc3 = acc0;
        const float* __restrict__ W1o = W1 + o;

        float cur[8];
#pragma unroll
        for (int j = 0; j < 8; ++j) cur[j] = W1o[j * OUTD];

        for (int batch = 0; batch < 28; ++batch) {     // 28*8 = 224
            const int fb = batch * 8;
            float nxt[8];
            if (batch < 27) {
#pragma unroll
                for (int j = 0; j < 8; ++j) nxt[j] = W1o[(fb + 8 + j) * OUTD];
            }
#pragma unroll
            for (int j = 0; j < 8; ++j) {
                const float w1v = cur[j];
                const int   f   = fb + j;
                acc0 = fmaf(ws[f      ], w1v, acc0);
                acc1 = fmaf(ws[f + 232], w1v, acc1);
                acc2 = fmaf(ws[f + 464], w1v, acc2);
                acc3 = fmaf(ws[f + 696], w1v, acc3);
            }
            if (batch < 27) {
#pragma unroll
                for (int j = 0; j < 8; ++j) cur[j] = nxt[j];
            }
        }
        for (int f = 224; f < N_BINS; ++f) {
            const float w1v = W1o[f * OUTD];
            acc0 = fmaf(ws[f      ], w1v, acc0);
            acc1 = fmaf(ws[f + 232], w1v, acc1);
            acc2 = fmaf(ws[f + 464], w1v, acc2);
            acc3 = fmaf(ws[f + 696], w1v, acc3);
        }
        const size_t rb = (size_t)r0 + h * 4;
        pred[(rb + 0) * OUTD + o] = sigmoidf_(acc0);
        pred[(rb + 1) * OUTD + o] = sigmoidf_(acc1);
        pred[(rb + 2) * OUTD + o] = sigmoidf_(acc2);
        pred[(rb + 3) * OUTD + o] = sigmoidf_(acc3);
    }
}

extern "C" void kernel_launch(void* const* d_in, const int* in_sizes, int n_in,
                              void* d_out, int out_size, void* d_ws, size_t ws_size,
                              hipStream_t stream) {
    const float* spec   = (const float*)d_in[0];
    const float* W_h    = (const float*)d_in[1];
    const float* W_e    = (const float*)d_in[2];
    const float* b_attn = (const float*)d_in[3];
    const float* v_w    = (const float*)d_in[4];
    const float* W1     = (const float*)d_in[5];
    const float* b1     = (const float*)d_in[6];

    const int n_rows = BB * TT;                    // 8192
    float* H = (float*)d_ws;                       // 4 MB
    float* E = H + (size_t)n_rows * MODEL;         // 4 MB
    // aEff: own region if ws allows (avoids H aliasing); else overlay on H
    // (safe: each k_score block writes only the H rows it already staged).
    float* aeff = (ws_size >= (size_t)12 * 1024 * 1024)
                ? E + (size_t)n_rows * MODEL       // +4 MB
                : H;

    float* pred  = (float*)d_out;                  // 8192*88
    float* a_out = pred + (size_t)n_rows * OUTD;   // 8192*61

    k_he   <<<n_rows / ROWS_HE, 256, 0, stream>>>(spec, W_h, W_e, b_attn, H, E);
    k_score<<<n_rows / 8,       256, 0, stream>>>(H, E, v_w, aeff, a_out);
    k_pool <<<n_rows / 8,       256, 0, stream>>>(spec, aeff, W1, b1, pred);
}